// Round 15
// baseline (79.291 us; speedup 1.0000x reference)
//
#include <hip/hip_runtime.h>
#include <cstdint>

typedef short bf16x8 __attribute__((ext_vector_type(8)));
typedef float f32x4 __attribute__((ext_vector_type(4)));
typedef uint16_t u16x4 __attribute__((ext_vector_type(4)));

#define MFMA_16x16x32(a, b, c) __builtin_amdgcn_mfma_f32_16x16x32_bf16((a), (b), (c), 0, 0, 0)

static constexpr int BATCH = 2;
static constexpr int HEADS = 12;
static constexpr int BH    = BATCH * HEADS;   // 24
static constexpr int NCTX  = 2048;
static constexpr int DH    = 64;
static constexpr int EMB   = 768;
static constexpr int NT    = NCTX / 64;       // 32 kv tiles

// 0.125 * log2(e): Q pre-scale so softmax runs in exp2 domain
static constexpr float QSCALE = 0.125f * 1.44269504088896340736f;

// ---------- bf16 helpers (raw-bit, RN rounding) ----------
__device__ __forceinline__ uint16_t f2bf(float x) {
    uint32_t u = __float_as_uint(x);
    u += 0x7FFFu + ((u >> 16) & 1u);
    return (uint16_t)(u >> 16);
}
__device__ __forceinline__ uint32_t cvt_pk_bf16(float lo, float hi) {
    uint32_t r;
    asm("v_cvt_pk_bf16_f32 %0, %1, %2" : "=v"(r) : "v"(lo), "v"(hi));
    return r;
}

// ---------- fused prep ----------
// blocks [0, 768):       V transpose -> PV fragment layout (R10, proven)
// blocks [768, 1536):    K convert -> QK fragment layout (same slot math)
// blocks [1536, 1536+576): W flat convert
// V frag: vf[((bh*32+t)*8 + 2f+h)*512 + (16g+c)*8 + j] = V[kv=64t+32h+8g+j][d=16f+c]
// K frag: kf[((bh*32+t)*8 + 2nf+kf)*512 + (16g+c)*8 + j] = K[kv=64t+16nf+c][d=32kf+8g+j]
__global__ __launch_bounds__(256) void k_prep(
        const float* __restrict__ v, uint16_t* __restrict__ vt,
        const float* __restrict__ kf32, uint16_t* __restrict__ kfr,
        const float* __restrict__ w32, uint16_t* __restrict__ wb, int n4w) {
    const int bid = blockIdx.x;
    const int t   = threadIdx.x;
    constexpr int NVB = BH * NT;   // 768

    if (bid < NVB) {
        // ---- V transpose+convert tile (R10 fragment layout, unchanged)
        __shared__ uint16_t tileT[64][72];   // [d][n_local]
        const int bh = bid >> 5;
        const int n0 = (bid & 31) * 64;

        const int r  = t >> 2;          // n-row within tile (0..63)
        const int cc = (t & 3) * 16;    // d-col base
        const float* vp = v + ((size_t)bh * NCTX + n0 + r) * DH + cc;
#pragma unroll
        for (int u = 0; u < 4; ++u) {
            float4 x = reinterpret_cast<const float4*>(vp)[u];
            tileT[cc + 4 * u + 0][r] = f2bf(x.x);
            tileT[cc + 4 * u + 1][r] = f2bf(x.y);
            tileT[cc + 4 * u + 2][r] = f2bf(x.z);
            tileT[cc + 4 * u + 3][r] = f2bf(x.w);
        }
        __syncthreads();

        const int l2 = t & 63;          // fragment lane
        const int s0 = t >> 6;          // 0..3
        const int gg = l2 >> 4;
        const int c2 = l2 & 15;
        uint16_t* vb = vt + ((size_t)bh * 32 + (n0 >> 6)) * 8 * 512;
#pragma unroll
        for (int u = 0; u < 2; ++u) {
            const int slot = s0 + 4 * u;        // 0..7
            const int f = slot >> 1, h = slot & 1;
            bf16x8 x = *reinterpret_cast<const bf16x8*>(&tileT[f * 16 + c2][h * 32 + 8 * gg]);
            *reinterpret_cast<bf16x8*>(vb + (size_t)slot * 512 + l2 * 8) = x;
        }
    } else if (bid < 2 * NVB) {
        // ---- K convert -> QK fragment layout (direct reads, no transpose)
        const int kb2 = bid - NVB;
        const int bh = kb2 >> 5;
        const int n0 = (kb2 & 31) * 64;
        const int l2 = t & 63;
        const int s0 = t >> 6;          // 0..3
        const int gg = l2 >> 4;
        const int c2 = l2 & 15;
        uint16_t* kb = kfr + ((size_t)bh * 32 + (n0 >> 6)) * 8 * 512;
#pragma unroll
        for (int u = 0; u < 2; ++u) {
            const int slot = s0 + 4 * u;        // 0..7
            const int nf = slot >> 1, kf = slot & 1;
            const float* kp = kf32 + ((size_t)bh * NCTX + n0 + 16 * nf + c2) * DH
                                   + 32 * kf + 8 * gg;
            float4 x0 = *reinterpret_cast<const float4*>(kp);
            float4 x1 = *reinterpret_cast<const float4*>(kp + 4);
            bf16x8 f;
            f[0] = (short)f2bf(x0.x); f[1] = (short)f2bf(x0.y);
            f[2] = (short)f2bf(x0.z); f[3] = (short)f2bf(x0.w);
            f[4] = (short)f2bf(x1.x); f[5] = (short)f2bf(x1.y);
            f[6] = (short)f2bf(x1.z); f[7] = (short)f2bf(x1.w);
            *reinterpret_cast<bf16x8*>(kb + (size_t)slot * 512 + l2 * 8) = f;
        }
    } else {
        // ---- W flat convert
        const int i = (bid - 2 * NVB) * 256 + t;
        if (i >= n4w) return;
        float4 x = reinterpret_cast<const float4*>(w32)[i];
        u16x4 hv = {f2bf(x.x), f2bf(x.y), f2bf(x.z), f2bf(x.w)};
        reinterpret_cast<u16x4*>(wb)[i] = hv;
    }
}

// ---------- flash attention: barrier-free ----------
// grid: (NCTX/64, BH), block: 256 (4 waves). Wave owns 16 q-rows and is fully
// independent: K AND V both come direct-from-global in fragment layout (one
// coalesced 1KB load per fragment), register-double-buffered with a full
// compute phase of latency cover each (the R10-proven V mechanism extended to
// K). No __syncthreads anywhere: LDS holds only the per-wave P round-trip.
// kr reload for tile t+1 is issued right after QK^T consumes tile t (WAR
// dependence pins it); cover = softmax+PV. vr for tile t issued at tile start;
// cover = QK^T+softmax. Softmax/P/PV/epilogue byte-identical to R13.
__global__ __launch_bounds__(256) void k_attn(
        const float* __restrict__ q, const uint16_t* __restrict__ kfr,
        const uint16_t* __restrict__ vf, uint16_t* __restrict__ xb) {
    const int bh = blockIdx.y;
    const int b  = bh / HEADS;
    const int h  = bh % HEADS;
    const int tid = threadIdx.x;
    const int w = tid >> 6;
    const int l = tid & 63;
    const int g = l >> 4;    // 16-lane group 0..3
    const int c = l & 15;

    __shared__ uint16_t P_s[4][16][72];   // [wave][q][kv] — strictly per-wave

    const int q0 = blockIdx.x * 64 + w * 16;

    // Q fragments: load fp32 direct, scale by 0.125*log2e, convert in-reg
    bf16x8 qa[2];
    {
        const float* qp = q + ((size_t)bh * NCTX + q0 + c) * DH + 8 * g;
#pragma unroll
        for (int kf = 0; kf < 2; ++kf) {
            float4 x0 = *reinterpret_cast<const float4*>(qp + kf * 32);
            float4 x1 = *reinterpret_cast<const float4*>(qp + kf * 32 + 4);
            bf16x8 f;
            f[0] = (short)f2bf(x0.x * QSCALE); f[1] = (short)f2bf(x0.y * QSCALE);
            f[2] = (short)f2bf(x0.z * QSCALE); f[3] = (short)f2bf(x0.w * QSCALE);
            f[4] = (short)f2bf(x1.x * QSCALE); f[5] = (short)f2bf(x1.y * QSCALE);
            f[6] = (short)f2bf(x1.z * QSCALE); f[7] = (short)f2bf(x1.w * QSCALE);
            qa[kf] = f;
        }
    }

    f32x4 zero = {0.f, 0.f, 0.f, 0.f};
    f32x4 o[4] = {zero, zero, zero, zero};
    float m = -1e30f;     // running max (log2 units), per q=c (uniform across groups)
    float lsum = 0.f;     // lane-partial softmax denominator for q=c

    // per-lane fragment bases (advance by (t*8+slot)*512)
    const uint16_t* kf_b = kfr + (size_t)bh * 32 * 8 * 512 + (size_t)l * 8;
    const uint16_t* vf_b = vf  + (size_t)bh * 32 * 8 * 512 + (size_t)l * 8;

    // prologue: K fragments for tile 0
    bf16x8 kr[8];
#pragma unroll
    for (int s2 = 0; s2 < 8; ++s2)
        kr[s2] = *reinterpret_cast<const bf16x8*>(kf_b + (size_t)s2 * 512);

    for (int t = 0; t < NT; ++t) {
        // V fragments for THIS tile (consumed at PV; cover = QK + softmax)
        bf16x8 vr[8];
#pragma unroll
        for (int s2 = 0; s2 < 8; ++s2)
            vr[s2] = *reinterpret_cast<const bf16x8*>(vf_b + ((size_t)t * 8 + s2) * 512);

        // ---- S^T = (K Q^T) single-bf16. s[nf][r] = S[kv=16nf+4g+r][q=c]
        f32x4 s[4] = {zero, zero, zero, zero};
        __builtin_amdgcn_s_setprio(1);
#pragma unroll
        for (int nf = 0; nf < 4; ++nf) {
#pragma unroll
            for (int kf = 0; kf < 2; ++kf)
                s[nf] = MFMA_16x16x32(kr[2 * nf + kf], qa[kf], s[nf]);
        }
        __builtin_amdgcn_s_setprio(0);

        // reload kr for the NEXT tile (clamped on last trip — values dead).
        // WAR on kr pins these loads after the QK MFMAs; cover = softmax + PV.
        {
            const int tn = (t + 1 < NT) ? (t + 1) : (NT - 1);
#pragma unroll
            for (int s2 = 0; s2 < 8; ++s2)
                kr[s2] = *reinterpret_cast<const bf16x8*>(kf_b + ((size_t)tn * 8 + s2) * 512);
        }

        // ---- per-lane partial max over this lane's 16 kv slots (tree, depth 4)
        float pm0 = fmaxf(fmaxf(s[0][0], s[0][1]), fmaxf(s[0][2], s[0][3]));
        float pm1 = fmaxf(fmaxf(s[1][0], s[1][1]), fmaxf(s[1][2], s[1][3]));
        float pm2 = fmaxf(fmaxf(s[2][0], s[2][1]), fmaxf(s[2][2], s[2][3]));
        float pm3 = fmaxf(fmaxf(s[3][0], s[3][1]), fmaxf(s[3][2], s[3][3]));
        float pmax = fmaxf(fmaxf(pm0, pm1), fmaxf(pm2, pm3));

        // deferred max, shfl-free common path (equivalence: see R9)
        if (!__all(pmax <= m + 11.0f)) {
            float smax = fmaxf(pmax, __shfl_xor(pmax, 16));
            smax = fmaxf(smax, __shfl_xor(smax, 32));
            float mnew = fmaxf(m, smax);
            float corr = __builtin_amdgcn_exp2f(m - mnew);
            m = mnew;
            lsum *= corr;
#pragma unroll
            for (int r = 0; r < 4; ++r) {
                float cr = __shfl(corr, 4 * g + r);   // corr for q-local 4g+r
#pragma unroll
                for (int f = 0; f < 4; ++f) o[f][r] *= cr;
            }
        }

        // p = exp2(s - m); pack pairs and write 4 contiguous kv per lane (b64)
#pragma unroll
        for (int nf = 0; nf < 4; ++nf) {
            float p0 = __builtin_amdgcn_exp2f(s[nf][0] - m);
            float p1 = __builtin_amdgcn_exp2f(s[nf][1] - m);
            float p2 = __builtin_amdgcn_exp2f(s[nf][2] - m);
            float p3 = __builtin_amdgcn_exp2f(s[nf][3] - m);
            lsum += (p0 + p1) + (p2 + p3);
            uint2 pk;
            pk.x = cvt_pk_bf16(p0, p1);
            pk.y = cvt_pk_bf16(p2, p3);
            *reinterpret_cast<uint2*>(&P_s[w][c][16 * nf + 4 * g]) = pk;
        }

        // ---- O += P V (V fragments already in registers)
        bf16x8 pa0 = *reinterpret_cast<const bf16x8*>(&P_s[w][c][8 * g]);
        bf16x8 pa1 = *reinterpret_cast<const bf16x8*>(&P_s[w][c][32 + 8 * g]);
        __builtin_amdgcn_s_setprio(1);
#pragma unroll
        for (int f = 0; f < 4; ++f) {
            o[f] = MFMA_16x16x32(pa0, vr[2 * f],     o[f]);
            o[f] = MFMA_16x16x32(pa1, vr[2 * f + 1], o[f]);
        }
        __builtin_amdgcn_s_setprio(0);
        // no barrier: waves are fully independent
    }

    // ---- epilogue: reduce l over the 4 groups, normalize, store bf16
    lsum += __shfl_xor(lsum, 16);
    lsum += __shfl_xor(lsum, 32);
    const float linv = 1.0f / lsum;

    const size_t xbase = ((size_t)b * NCTX + q0) * EMB + h * DH;
#pragma unroll
    for (int r = 0; r < 4; ++r) {
        float lr = __shfl(linv, 4 * g + r);   // 1/l for q-local 4g+r
#pragma unroll
        for (int f = 0; f < 4; ++f) {
            float v = o[f][r] * lr;
            size_t addr = xbase + (size_t)(4 * g + r) * EMB + f * 16 + c;
            xb[addr] = f2bf(v);
        }
    }
}

// ---------- projection GEMM: Y[4096x768] = X @ W^T + bias (single-bf16) ----------
// 64-wide k rounds, clamped-index register prefetch (R9/R10/R13, unchanged).
__global__ __launch_bounds__(256) void k_proj(
        const uint16_t* __restrict__ xb, const uint16_t* __restrict__ wb,
        const float* __restrict__ bias, float* __restrict__ out) {
    const int tid = threadIdx.x;
    const int w = tid >> 6;
    const int l = tid & 63;
    const int g = l >> 4;
    const int c = l & 15;
    const int m0 = blockIdx.x * 64 + w * 16;
    const int n0 = blockIdx.y * 64;

    __shared__ uint16_t W_s[64][72];

    f32x4 zero = {0.f, 0.f, 0.f, 0.f};
    f32x4 acc[4] = {zero, zero, zero, zero};

    const int srow = tid >> 2;   // 0..63
    const int sch  = tid & 3;    // 0..3
    constexpr int ROUNDS = EMB / 64;   // 12

    const uint16_t* whp = wb + (size_t)(n0 + srow) * EMB + sch * 8;
    const uint16_t* xhp = xb + (size_t)(m0 + c) * EMB + 8 * g;

    bf16x8 w0 = *reinterpret_cast<const bf16x8*>(whp);
    bf16x8 w1 = *reinterpret_cast<const bf16x8*>(whp + 32);
    bf16x8 a0 = *reinterpret_cast<const bf16x8*>(xhp);
    bf16x8 a1 = *reinterpret_cast<const bf16x8*>(xhp + 32);

    for (int rd = 0; rd < ROUNDS; ++rd) {
        __syncthreads();
        *reinterpret_cast<bf16x8*>(&W_s[srow][sch * 8])      = w0;
        *reinterpret_cast<bf16x8*>(&W_s[srow][32 + sch * 8]) = w1;
        __syncthreads();

        const int rn = (rd + 1 < ROUNDS) ? (rd + 1) : (ROUNDS - 1);
        bf16x8 w0n = *reinterpret_cast<const bf16x8*>(whp + (size_t)rn * 64);
        bf16x8 w1n = *reinterpret_cast<const bf16x8*>(whp + (size_t)rn * 64 + 32);
        bf16x8 a0n = *reinterpret_cast<const bf16x8*>(xhp + (size_t)rn * 64);
        bf16x8 a1n = *reinterpret_cast<const bf16x8*>(xhp + (size_t)rn * 64 + 32);

        __builtin_amdgcn_s_setprio(1);
#pragma unroll
        for (int nf = 0; nf < 4; ++nf) {
            bf16x8 b0 = *reinterpret_cast<const bf16x8*>(&W_s[nf * 16 + c][8 * g]);
            bf16x8 b1 = *reinterpret_cast<const bf16x8*>(&W_s[nf * 16 + c][32 + 8 * g]);
            acc[nf] = MFMA_16x16x32(a0, b0, acc[nf]);
            acc[nf] = MFMA_16x16x32(a1, b1, acc[nf]);
        }
        __builtin_amdgcn_s_setprio(0);

        w0 = w0n; w1 = w1n; a0 = a0n; a1 = a1n;
    }

#pragma unroll
    for (int nf = 0; nf < 4; ++nf) {
#pragma unroll
        for (int r = 0; r < 4; ++r) {
            int row = m0 + g * 4 + r;
            int col = n0 + nf * 16 + c;
            out[(size_t)row * EMB + col] = acc[nf][r] + bias[col];
        }
    }
}

extern "C" void kernel_launch(void* const* d_in, const int* in_sizes, int n_in,
                              void* d_out, int out_size, void* d_ws, size_t ws_size,
                              hipStream_t stream) {
    const float* q    = (const float*)d_in[0];
    const float* k    = (const float*)d_in[1];
    const float* v    = (const float*)d_in[2];
    const float* pw   = (const float*)d_in[3];
    const float* pb   = (const float*)d_in[4];
    float* out = (float*)d_out;

    const size_t nqkv = (size_t)BH * NCTX * DH;     // 3,145,728
    const size_t nx   = (size_t)BATCH * NCTX * EMB; // 3,145,728
    const size_t nw   = (size_t)EMB * EMB;          //   589,824

    uint8_t* ws = (uint8_t*)d_ws;
    uint16_t* kfr = (uint16_t*)ws;             ws += nqkv * 2;   // K fragment layout
    uint16_t* vfr = (uint16_t*)ws;             ws += nqkv * 2;   // V fragment layout
    uint16_t* xb  = (uint16_t*)ws;             ws += nx * 2;
    uint16_t* wb  = (uint16_t*)ws;             ws += nw * 2;

    // fused prep: V frags (768) + K frags (768) + W convert (576)
    const int n4w = (int)(nw / 4);
    const int nprep = 2 * BH * NT + (n4w + 255) / 256;
    k_prep<<<nprep, 256, 0, stream>>>(v, vfr, k, kfr, pw, wb, n4w);

    // attention (barrier-free, K+V direct fragment loads)
    k_attn<<<dim3(NCTX / 64, BH), 256, 0, stream>>>(q, kfr, vfr, xb);

    // projection
    k_proj<<<dim3((BATCH * NCTX) / 64, EMB / 64), 256, 0, stream>>>(xb, wb, pb, out);
}

// Round 16
// 74.963 us; speedup vs baseline: 1.0577x; 1.0577x over previous
//
#include <hip/hip_runtime.h>
#include <cstdint>

typedef short bf16x8 __attribute__((ext_vector_type(8)));
typedef float f32x4 __attribute__((ext_vector_type(4)));
typedef uint16_t u16x4 __attribute__((ext_vector_type(4)));

#define MFMA_16x16x32(a, b, c) __builtin_amdgcn_mfma_f32_16x16x32_bf16((a), (b), (c), 0, 0, 0)

static constexpr int BATCH = 2;
static constexpr int HEADS = 12;
static constexpr int BH    = BATCH * HEADS;   // 24
static constexpr int NCTX  = 2048;
static constexpr int DH    = 64;
static constexpr int EMB   = 768;

// 0.125 * log2(e): Q pre-scale so softmax runs in exp2 domain
static constexpr float QSCALE = 0.125f * 1.44269504088896340736f;

// ---------- bf16 helpers (raw-bit, RN rounding) ----------
__device__ __forceinline__ uint16_t f2bf(float x) {
    uint32_t u = __float_as_uint(x);
    u += 0x7FFFu + ((u >> 16) & 1u);
    return (uint16_t)(u >> 16);
}
__device__ __forceinline__ uint32_t cvt_pk_bf16(float lo, float hi) {
    uint32_t r;
    asm("v_cvt_pk_bf16_f32 %0, %1, %2" : "=v"(r) : "v"(lo), "v"(hi));
    return r;
}

// ---------- fused prep: V transpose->fragment layout + K/W convert ----------
// blocks [0, 768):            V transpose (bh = bid>>5, n0 = (bid&31)*64)
// blocks [768, 768+3648):     flat K (n4k) then W (n4w) float4->bf16 convert
// V fragment layout (R10): vf[((bh*32+t)*8 + slot)*512 + l*8 + j]
//   = V[kv=64t+32h+8g+j][d=16f+c], slot=2f+h, l=16g+c.
__global__ __launch_bounds__(256) void k_prep(
        const float* __restrict__ v, uint16_t* __restrict__ vt,
        const float* __restrict__ kf32, uint16_t* __restrict__ kb, int n4k,
        const float* __restrict__ w32, uint16_t* __restrict__ wb, int n4w) {
    const int bid = blockIdx.x;
    const int t   = threadIdx.x;

    if (bid < BH * (NCTX / 64)) {
        // ---- V transpose+convert tile
        __shared__ uint16_t tileT[64][72];   // [d][n_local]
        const int bh = bid >> 5;
        const int n0 = (bid & 31) * 64;

        const int r  = t >> 2;          // n-row within tile (0..63)
        const int cc = (t & 3) * 16;    // d-col base
        const float* vp = v + ((size_t)bh * NCTX + n0 + r) * DH + cc;
#pragma unroll
        for (int u = 0; u < 4; ++u) {
            float4 x = reinterpret_cast<const float4*>(vp)[u];
            tileT[cc + 4 * u + 0][r] = f2bf(x.x);
            tileT[cc + 4 * u + 1][r] = f2bf(x.y);
            tileT[cc + 4 * u + 2][r] = f2bf(x.z);
            tileT[cc + 4 * u + 3][r] = f2bf(x.w);
        }
        __syncthreads();

        const int l2 = t & 63;          // fragment lane
        const int s0 = t >> 6;          // 0..3
        const int gg = l2 >> 4;
        const int c2 = l2 & 15;
        uint16_t* vb = vt + ((size_t)bh * 32 + (n0 >> 6)) * 8 * 512;
#pragma unroll
        for (int u = 0; u < 2; ++u) {
            const int slot = s0 + 4 * u;        // 0..7
            const int f = slot >> 1, h = slot & 1;
            bf16x8 x = *reinterpret_cast<const bf16x8*>(&tileT[f * 16 + c2][h * 32 + 8 * gg]);
            *reinterpret_cast<bf16x8*>(vb + (size_t)slot * 512 + l2 * 8) = x;
        }
    } else {
        // ---- flat convert: K then W
        const int i = (bid - BH * (NCTX / 64)) * 256 + t;
        const float* src; uint16_t* dst; int j;
        if (i < n4k) { src = kf32; dst = kb; j = i; }
        else {
            j = i - n4k;
            if (j >= n4w) return;
            src = w32; dst = wb;
        }
        float4 x = reinterpret_cast<const float4*>(src)[j];
        u16x4 hv = {f2bf(x.x), f2bf(x.y), f2bf(x.z), f2bf(x.w)};
        reinterpret_cast<u16x4*>(dst)[j] = hv;
    }
}

// ---------- flash attention (R10/R13 structure, proven optimum) ----------
// grid: (NCTX/64, BH), block: 256 (4 waves). Wave owns 16 q-rows.
// K staged in double-buffered LDS (shared across 4 waves — L1 can't absorb
// 4x K duplication, per R15); V in registers via fragment-contiguous layout
// (8 coalesced 1KB loads per tile at tile start — L1 absorbs V fine, per R10).
// Swapped QK^T, exp2 domain, shfl-free deferred max, vectorized P round-trip.
__global__ __launch_bounds__(256) void k_attn(
        const float* __restrict__ q, const uint16_t* __restrict__ kb,
        const uint16_t* __restrict__ vf, uint16_t* __restrict__ xb) {
    const int bh = blockIdx.y;
    const int b  = bh / HEADS;
    const int h  = bh % HEADS;
    const int tid = threadIdx.x;
    const int w = tid >> 6;
    const int l = tid & 63;
    const int g = l >> 4;    // 16-lane group 0..3
    const int c = l & 15;

    __shared__ uint16_t K_s[2][64][72];
    __shared__ uint16_t P_s[4][16][72];   // [wave][q][kv]

    const int q0 = blockIdx.x * 64 + w * 16;

    // Q fragments: load fp32 direct, scale by 0.125*log2e, convert in-reg
    bf16x8 qa[2];
    {
        const float* qp = q + ((size_t)bh * NCTX + q0 + c) * DH + 8 * g;
#pragma unroll
        for (int kf = 0; kf < 2; ++kf) {
            float4 x0 = *reinterpret_cast<const float4*>(qp + kf * 32);
            float4 x1 = *reinterpret_cast<const float4*>(qp + kf * 32 + 4);
            bf16x8 f;
            f[0] = (short)f2bf(x0.x * QSCALE); f[1] = (short)f2bf(x0.y * QSCALE);
            f[2] = (short)f2bf(x0.z * QSCALE); f[3] = (short)f2bf(x0.w * QSCALE);
            f[4] = (short)f2bf(x1.x * QSCALE); f[5] = (short)f2bf(x1.y * QSCALE);
            f[6] = (short)f2bf(x1.z * QSCALE); f[7] = (short)f2bf(x1.w * QSCALE);
            qa[kf] = f;
        }
    }

    f32x4 zero = {0.f, 0.f, 0.f, 0.f};
    f32x4 o[4] = {zero, zero, zero, zero};
    float m = -1e30f;     // running max (log2 units), per q=c (uniform across groups)
    float lsum = 0.f;     // lane-partial softmax denominator for q=c

    // K staging decomposition: 256 thr -> 32 rows x 8 chunks, two row-passes
    const int srow = tid >> 3;      // 0..31
    const int sch  = tid & 7;       // 0..7

    const uint16_t* kb_b = kb + (size_t)bh * NCTX * DH + srow * DH + sch * 8;
    // per-lane V fragment base: vf + bh*32*8*512 + l*8  (advance by (t*8+s)*512)
    const uint16_t* vf_b = vf + (size_t)bh * 32 * 8 * 512 + (size_t)l * 8;

    // prologue: stage K tile 0 into buffer 0
    {
        bf16x8 a0 = *reinterpret_cast<const bf16x8*>(kb_b);
        bf16x8 a1 = *reinterpret_cast<const bf16x8*>(kb_b + 32 * DH);
        *reinterpret_cast<bf16x8*>(&K_s[0][srow][sch * 8])      = a0;
        *reinterpret_cast<bf16x8*>(&K_s[0][srow + 32][sch * 8]) = a1;
    }
    __syncthreads();

    for (int t = 0; t < NCTX / 64; ++t) {
        const int cur = t & 1;
        const int nxt = cur ^ 1;

        // issue next-K-tile loads early (hide latency under compute)
        bf16x8 nk0, nk1;
        const bool pf = (t + 1) < NCTX / 64;
        if (pf) {
            const size_t ko = (size_t)(t + 1) * 64 * DH;
            nk0 = *reinterpret_cast<const bf16x8*>(kb_b + ko);
            nk1 = *reinterpret_cast<const bf16x8*>(kb_b + ko + 32 * DH);
        }

        // issue THIS tile's V fragment loads now (consumed at PV, ~full tile away)
        bf16x8 vr[8];
#pragma unroll
        for (int s = 0; s < 8; ++s)
            vr[s] = *reinterpret_cast<const bf16x8*>(vf_b + ((size_t)t * 8 + s) * 512);

        // ---- S^T = (K Q^T) single-bf16. s[nf][r] = S[kv=16nf+4g+r][q=c]
        f32x4 s[4] = {zero, zero, zero, zero};
        __builtin_amdgcn_s_setprio(1);
#pragma unroll
        for (int nf = 0; nf < 4; ++nf) {
#pragma unroll
            for (int kf = 0; kf < 2; ++kf) {
                bf16x8 bhf = *reinterpret_cast<const bf16x8*>(&K_s[cur][nf * 16 + c][kf * 32 + 8 * g]);
                s[nf] = MFMA_16x16x32(bhf, qa[kf], s[nf]);
            }
        }
        __builtin_amdgcn_s_setprio(0);

        // ---- per-lane partial max over this lane's 16 kv slots (tree, depth 4)
        float pm0 = fmaxf(fmaxf(s[0][0], s[0][1]), fmaxf(s[0][2], s[0][3]));
        float pm1 = fmaxf(fmaxf(s[1][0], s[1][1]), fmaxf(s[1][2], s[1][3]));
        float pm2 = fmaxf(fmaxf(s[2][0], s[2][1]), fmaxf(s[2][2], s[2][3]));
        float pm3 = fmaxf(fmaxf(s[3][0], s[3][1]), fmaxf(s[3][2], s[3][3]));
        float pmax = fmaxf(fmaxf(pm0, pm1), fmaxf(pm2, pm3));

        // deferred max, shfl-free common path (equivalence: see R9)
        if (!__all(pmax <= m + 11.0f)) {
            float smax = fmaxf(pmax, __shfl_xor(pmax, 16));
            smax = fmaxf(smax, __shfl_xor(smax, 32));
            float mnew = fmaxf(m, smax);
            float corr = __builtin_amdgcn_exp2f(m - mnew);
            m = mnew;
            lsum *= corr;
#pragma unroll
            for (int r = 0; r < 4; ++r) {
                float cr = __shfl(corr, 4 * g + r);   // corr for q-local 4g+r
#pragma unroll
                for (int f = 0; f < 4; ++f) o[f][r] *= cr;
            }
        }

        // p = exp2(s - m); pack pairs and write 4 contiguous kv per lane (b64)
#pragma unroll
        for (int nf = 0; nf < 4; ++nf) {
            float p0 = __builtin_amdgcn_exp2f(s[nf][0] - m);
            float p1 = __builtin_amdgcn_exp2f(s[nf][1] - m);
            float p2 = __builtin_amdgcn_exp2f(s[nf][2] - m);
            float p3 = __builtin_amdgcn_exp2f(s[nf][3] - m);
            lsum += (p0 + p1) + (p2 + p3);
            uint2 pk;
            pk.x = cvt_pk_bf16(p0, p1);
            pk.y = cvt_pk_bf16(p2, p3);
            *reinterpret_cast<uint2*>(&P_s[w][c][16 * nf + 4 * g]) = pk;
        }

        // ---- O += P V (V fragments already in registers)
        bf16x8 pa0 = *reinterpret_cast<const bf16x8*>(&P_s[w][c][8 * g]);
        bf16x8 pa1 = *reinterpret_cast<const bf16x8*>(&P_s[w][c][32 + 8 * g]);
        __builtin_amdgcn_s_setprio(1);
#pragma unroll
        for (int f = 0; f < 4; ++f) {
            o[f] = MFMA_16x16x32(pa0, vr[2 * f],     o[f]);
            o[f] = MFMA_16x16x32(pa1, vr[2 * f + 1], o[f]);
        }
        __builtin_amdgcn_s_setprio(0);

        // ---- write prefetched K tile to the ALTERNATE buffer, then one barrier
        if (pf) {
            *reinterpret_cast<bf16x8*>(&K_s[nxt][srow][sch * 8])      = nk0;
            *reinterpret_cast<bf16x8*>(&K_s[nxt][srow + 32][sch * 8]) = nk1;
        }
        __syncthreads();
    }

    // ---- epilogue: reduce l over the 4 groups, normalize, store bf16
    lsum += __shfl_xor(lsum, 16);
    lsum += __shfl_xor(lsum, 32);
    const float linv = 1.0f / lsum;

    const size_t xbase = ((size_t)b * NCTX + q0) * EMB + h * DH;
#pragma unroll
    for (int r = 0; r < 4; ++r) {
        float lr = __shfl(linv, 4 * g + r);   // 1/l for q-local 4g+r
#pragma unroll
        for (int f = 0; f < 4; ++f) {
            float v = o[f][r] * lr;
            size_t addr = xbase + (size_t)(4 * g + r) * EMB + f * 16 + c;
            xb[addr] = f2bf(v);
        }
    }
}

// ---------- projection GEMM: Y[4096x768] = X @ W^T + bias (single-bf16) ----------
// 64-wide k rounds, clamped-index register prefetch (R9/R10, unchanged).
__global__ __launch_bounds__(256) void k_proj(
        const uint16_t* __restrict__ xb, const uint16_t* __restrict__ wb,
        const float* __restrict__ bias, float* __restrict__ out) {
    const int tid = threadIdx.x;
    const int w = tid >> 6;
    const int l = tid & 63;
    const int g = l >> 4;
    const int c = l & 15;
    const int m0 = blockIdx.x * 64 + w * 16;
    const int n0 = blockIdx.y * 64;

    __shared__ uint16_t W_s[64][72];

    f32x4 zero = {0.f, 0.f, 0.f, 0.f};
    f32x4 acc[4] = {zero, zero, zero, zero};

    const int srow = tid >> 2;   // 0..63
    const int sch  = tid & 3;    // 0..3
    constexpr int ROUNDS = EMB / 64;   // 12

    const uint16_t* whp = wb + (size_t)(n0 + srow) * EMB + sch * 8;
    const uint16_t* xhp = xb + (size_t)(m0 + c) * EMB + 8 * g;

    bf16x8 w0 = *reinterpret_cast<const bf16x8*>(whp);
    bf16x8 w1 = *reinterpret_cast<const bf16x8*>(whp + 32);
    bf16x8 a0 = *reinterpret_cast<const bf16x8*>(xhp);
    bf16x8 a1 = *reinterpret_cast<const bf16x8*>(xhp + 32);

    for (int rd = 0; rd < ROUNDS; ++rd) {
        __syncthreads();
        *reinterpret_cast<bf16x8*>(&W_s[srow][sch * 8])      = w0;
        *reinterpret_cast<bf16x8*>(&W_s[srow][32 + sch * 8]) = w1;
        __syncthreads();

        const int rn = (rd + 1 < ROUNDS) ? (rd + 1) : (ROUNDS - 1);
        bf16x8 w0n = *reinterpret_cast<const bf16x8*>(whp + (size_t)rn * 64);
        bf16x8 w1n = *reinterpret_cast<const bf16x8*>(whp + (size_t)rn * 64 + 32);
        bf16x8 a0n = *reinterpret_cast<const bf16x8*>(xhp + (size_t)rn * 64);
        bf16x8 a1n = *reinterpret_cast<const bf16x8*>(xhp + (size_t)rn * 64 + 32);

        __builtin_amdgcn_s_setprio(1);
#pragma unroll
        for (int nf = 0; nf < 4; ++nf) {
            bf16x8 b0 = *reinterpret_cast<const bf16x8*>(&W_s[nf * 16 + c][8 * g]);
            bf16x8 b1 = *reinterpret_cast<const bf16x8*>(&W_s[nf * 16 + c][32 + 8 * g]);
            acc[nf] = MFMA_16x16x32(a0, b0, acc[nf]);
            acc[nf] = MFMA_16x16x32(a1, b1, acc[nf]);
        }
        __builtin_amdgcn_s_setprio(0);

        w0 = w0n; w1 = w1n; a0 = a0n; a1 = a1n;
    }

#pragma unroll
    for (int nf = 0; nf < 4; ++nf) {
#pragma unroll
        for (int r = 0; r < 4; ++r) {
            int row = m0 + g * 4 + r;
            int col = n0 + nf * 16 + c;
            out[(size_t)row * EMB + col] = acc[nf][r] + bias[col];
        }
    }
}

extern "C" void kernel_launch(void* const* d_in, const int* in_sizes, int n_in,
                              void* d_out, int out_size, void* d_ws, size_t ws_size,
                              hipStream_t stream) {
    const float* q    = (const float*)d_in[0];
    const float* k    = (const float*)d_in[1];
    const float* v    = (const float*)d_in[2];
    const float* pw   = (const float*)d_in[3];
    const float* pb   = (const float*)d_in[4];
    float* out = (float*)d_out;

    const size_t nqkv = (size_t)BH * NCTX * DH;     // 3,145,728
    const size_t nx   = (size_t)BATCH * NCTX * EMB; // 3,145,728
    const size_t nw   = (size_t)EMB * EMB;          //   589,824

    uint8_t* ws = (uint8_t*)d_ws;
    uint16_t* kb = (uint16_t*)ws;              ws += nqkv * 2;
    uint16_t* vf = (uint16_t*)ws;              ws += nqkv * 2;
    uint16_t* xb = (uint16_t*)ws;              ws += nx * 2;
    uint16_t* wb = (uint16_t*)ws;              ws += nw * 2;

    // fused prep: V transpose (768 blocks) + K/W convert (3648 blocks)
    const int n4k = (int)(nqkv / 4);
    const int n4w = (int)(nw / 4);
    const int nprep = BH * (NCTX / 64) + (n4k + n4w + 255) / 256;
    k_prep<<<nprep, 256, 0, stream>>>(v, vf, k, kb, n4k, pw, wb, n4w);

    // attention (R13 structure: K staged in LDS, V direct fragments)
    k_attn<<<dim3(NCTX / 64, BH), 256, 0, stream>>>(q, kb, vf, xb);

    // projection
    k_proj<<<dim3((BATCH * NCTX) / 64, EMB / 64), 256, 0, stream>>>(xb, wb, pb, out);
}